// Round 16
// baseline (255.655 us; speedup 1.0000x reference)
//
#include <hip/hip_runtime.h>

#define NB 8
#define NN 256
#define NS 128
#define NM 8192
#define NK 200
#define KP1 201
#define FEPS 1e-9f
#define GROUP_BLOCKS (NB * NN)   // 2048 group units
#define CD1B_BLOCKS 256
#define GRID_TOTAL (GROUP_BLOCKS + CD1B_BLOCKS)   // 2304
#define HBINS 2048

// ws layout (floats):
//  [0    .. 4096)  float2 per group unit {t1, t2}    (cd2 partials)
//  [4096 .. 6144)  float per group unit  cd1a        (cd1 term 1)
//  [6144 .. 6400)  float per cd1b unit   t4          (cd1 term 2)
//  [6400]          unsigned counter (memset to 0 per launch)
#define CD1A_OFF (2 * GROUP_BLOCKS)
#define T4_OFF   (3 * GROUP_BLOCKS)
#define CNT_OFF  (3 * GROUP_BLOCKS + CD1B_BLOCKS)

// ---------- reduction helpers (256 threads = 4 waves) ----------
__device__ __forceinline__ float block_sum_f(float v, float* redf) {
    const int tid = threadIdx.x, w = tid >> 6, l = tid & 63;
    for (int o = 32; o; o >>= 1) v += __shfl_xor(v, o);
    if (l == 0) redf[w] = v;
    __syncthreads();
    float t = redf[0] + redf[1] + redf[2] + redf[3];
    __syncthreads();
    return t;
}

__device__ __forceinline__ int block_excl_scan_i(int v, int* redi, int tid, int& total) {
    const int l = tid & 63, w = tid >> 6;
    int x = v;
    for (int o = 1; o < 64; o <<= 1) { int y = __shfl_up(x, o); if (l >= o) x += y; }
    if (l == 63) redi[w] = x;
    __syncthreads();
    int woff = 0;
#pragma unroll
    for (int j = 0; j < 4; ++j) { if (j < w) woff += redi[j]; }
    total = redi[0] + redi[1] + redi[2] + redi[3];
    int ex = woff + x - v;
    __syncthreads();
    return ex;
}

__device__ __forceinline__ int find_bin(int* hist, int nbins, int& rem,
                                        int* redi, int* ibc, int tid) {
    const int C = nbins >> 8;
    const int base = tid * C;
    int local = 0;
    for (int j = 0; j < C; ++j) local += hist[base + j];
    int total;
    int ex = block_excl_scan_i(local, redi, tid, total);
    if (ex < rem && rem <= ex + local) {
        int run = ex;
        for (int j = 0; j < C; ++j) {
            int h = hist[base + j];
            if (run + h >= rem) { ibc[0] = base + j; ibc[1] = rem - run; break; }
            run += h;
        }
    }
    __syncthreads();
    int bin = ibc[0]; rem = ibc[1];
    __syncthreads();
    return bin;
}

// ---------- fused kernel: 2048 group blocks + 256 cd1b blocks ----------
// Partials written via device-scope atomics; last finishing block reduces
// them and writes out[0..2] (no second kernel dispatch).
__global__ __launch_bounds__(256)
void k_main(const float* __restrict__ means, const float* __restrict__ sp,
            const float* __restrict__ gt, float* __restrict__ ws,
            float* __restrict__ out) {
    __shared__ int   hist[HBINS];                 // 8KB; reused: cd1b mpool, rowred
    __shared__ float gx[NK], gy[NK], gz[NK], g2s[NK];
    __shared__ float sx[NS], sy[NS], sz[NS];
    __shared__ float redf[4];
    __shared__ int   redi[4];
    __shared__ int   ibc[2];
    __shared__ int   lastFlag;

    const int tid = threadIdx.x;
    const int w = tid >> 6, l = tid & 63;

    if (blockIdx.x >= GROUP_BLOCKS) {
        // ---- cd1 term 2: per (b,m) min over the 256 means ----
        const int blk = blockIdx.x - GROUP_BLOCKS;
        const int b = blk >> 5;
        const int m = ((blk & 31) << 8) + tid;
        float* mxs = (float*)hist;                // 768 floats in 8KB pool
        float* mys = mxs + NN;
        float* mzs = mys + NN;
        const float* mb = means + (size_t)b * NN * 3;
        mxs[tid] = mb[tid * 3 + 0];
        mys[tid] = mb[tid * 3 + 1];
        mzs[tid] = mb[tid * 3 + 2];
        __syncthreads();
        const float* gp = gt + ((size_t)b * NM + m) * 3;
        const float px = gp[0], py = gp[1], pz = gp[2];
        float mn = 3.4e38f;
#pragma unroll 8
        for (int n = 0; n < NN; ++n) {
            float dx = px - mxs[n], dy = py - mys[n], dz = pz - mzs[n];
            mn = fminf(mn, fmaf(dx, dx, fmaf(dy, dy, dz * dz)));
        }
        float d2 = sqrtf(fmaxf(mn, FEPS));
        float t4 = block_sum_f(d2, redf);
        if (tid == 0) atomicExch(&ws[T4_OFF + blk], t4);
    } else {
        // ---- group path: one block per (b,n) ----
        const int bn = blockIdx.x;
        const int b  = bn >> 8;

        const float* spb = sp + (size_t)bn * NS * 3;
        if (tid < NS) {
            sx[tid] = spb[tid * 3 + 0];
            sy[tid] = spb[tid * 3 + 1];
            sz[tid] = spb[tid * 3 + 2];
        }
        const float mx = means[bn * 3 + 0];
        const float my = means[bn * 3 + 1];
        const float mz = means[bn * 3 + 2];
        const float* g = gt + (size_t)b * NM * 3;

        // distances: contiguous float4 loads; thread owns m in [tid*32, tid*32+32)
        const float* gtb = g + tid * 96;
        float vd[32];
        float vmin = 3.4e38f; int varg = -1;
#pragma unroll
        for (int c = 0; c < 8; ++c) {
            float4 f0 = *(const float4*)(gtb + c * 12);
            float4 f1 = *(const float4*)(gtb + c * 12 + 4);
            float4 f2 = *(const float4*)(gtb + c * 12 + 8);
            float px[4] = {f0.x, f0.w, f1.z, f2.y};
            float py[4] = {f0.y, f1.x, f1.w, f2.z};
            float pz[4] = {f0.z, f1.y, f2.x, f2.w};
#pragma unroll
            for (int j = 0; j < 4; ++j) {
                int i = c * 4 + j;
                float dx = mx - px[j], dy = my - py[j], dz = mz - pz[j];
                float d = fmaf(dx, dx, fmaf(dy, dy, dz * dz));
                vd[i] = d;
                if (d < vmin) { vmin = d; varg = tid * 32 + i; }
            }
        }

        // block argmin (value,index), lowest index on ties
        for (int o = 32; o; o >>= 1) {
            float ov = __shfl_xor(vmin, o);
            int   oi = __shfl_xor(varg, o);
            if (ov < vmin || (ov == vmin && oi < varg)) { vmin = ov; varg = oi; }
        }
        if (l == 0) { redf[w] = vmin; redi[w] = varg; }
        __syncthreads();
        float dmin = redf[0]; int m0 = redi[0];
#pragma unroll
        for (int i = 1; i < 4; ++i) {
            if (redf[i] < dmin || (redf[i] == dmin && redi[i] < m0)) { dmin = redf[i]; m0 = redi[i]; }
        }
        if (tid == 0) atomicExch(&ws[CD1A_OFF + bn], sqrtf(fmaxf(dmin, FEPS)));
        __syncthreads();

        // exact 201st-smallest via 3-level histogram radix
        int rem = KP1;
        unsigned prefix;
        for (int j = tid; j < HBINS; j += 256) hist[j] = 0;
        __syncthreads();
#pragma unroll
        for (int i = 0; i < 32; ++i) atomicAdd(&hist[__float_as_uint(vd[i]) >> 20], 1);
        __syncthreads();
        prefix = (unsigned)find_bin(hist, 2048, rem, redi, ibc, tid);
        for (int j = tid; j < HBINS; j += 256) hist[j] = 0;
        __syncthreads();
#pragma unroll
        for (int i = 0; i < 32; ++i) {
            unsigned u = __float_as_uint(vd[i]);
            if ((u >> 20) == prefix) atomicAdd(&hist[(u >> 9) & 2047], 1);
        }
        __syncthreads();
        prefix = (prefix << 11) | (unsigned)find_bin(hist, 2048, rem, redi, ibc, tid);
        for (int j = tid; j < 512; j += 256) hist[j] = 0;
        __syncthreads();
#pragma unroll
        for (int i = 0; i < 32; ++i) {
            unsigned u = __float_as_uint(vd[i]);
            if ((u >> 9) == prefix) atomicAdd(&hist[u & 511], 1);
        }
        __syncthreads();
        const unsigned X = (prefix << 9) | (unsigned)find_bin(hist, 512, rem, redi, ibc, tid);

        // gather: strict-less via scan, ties fill; |g|^2 into LDS
        int c = 0;
#pragma unroll
        for (int i = 0; i < 32; ++i) {
            int m = tid * 32 + i;
            c += (m != m0 && __float_as_uint(vd[i]) < X);
        }
        int total;
        int p = block_excl_scan_i(c, redi, tid, total);
#pragma unroll
        for (int i = 0; i < 32; ++i) {
            int m = tid * 32 + i;
            if (m != m0 && __float_as_uint(vd[i]) < X) {
                float x = g[m * 3 + 0], y = g[m * 3 + 1], z = g[m * 3 + 2];
                gx[p] = x; gy[p] = y; gz[p] = z;
                g2s[p] = fmaf(x, x, fmaf(y, y, z * z));
                ++p;
            }
        }
        if (tid == 0) ibc[0] = total;
        __syncthreads();
#pragma unroll
        for (int i = 0; i < 32; ++i) {
            int m = tid * 32 + i;
            if (m != m0 && __float_as_uint(vd[i]) == X) {
                int q = atomicAdd(&ibc[0], 1);
                if (q < NK) {
                    float x = g[m * 3 + 0], y = g[m * 3 + 1], z = g[m * 3 + 2];
                    gx[q] = x; gy[q] = y; gz[q] = z;
                    g2s[q] = fmaf(x, x, fmaf(y, y, z * z));
                }
            }
        }
        __syncthreads();

        // fused chamfer via d = |s|^2 + |g|^2 - 2 s.g
        const int ts = tid & 15, tk = tid >> 4;
        float psx[8], psy[8], psz[8], s2[8];
#pragma unroll
        for (int j = 0; j < 8; ++j) {
            int s = ts * 8 + j;
            float x = sx[s], y = sy[s], z = sz[s];
            s2[j] = fmaf(x, x, fmaf(y, y, z * z));
            psx[j] = -2.0f * x; psy[j] = -2.0f * y; psz[j] = -2.0f * z;
        }
        float rowacc[8];
#pragma unroll
        for (int j = 0; j < 8; ++j) rowacc[j] = 3.4e38f;
        float d2acc = 0.0f;
#pragma unroll
        for (int ip = 0; ip < 6; ++ip) {
            int k0 = tk + 32 * ip, k1 = k0 + 16;
            float qx0 = gx[k0], qy0 = gy[k0], qz0 = gz[k0], hg0 = g2s[k0];
            float qx1 = gx[k1], qy1 = gy[k1], qz1 = gz[k1], hg1 = g2s[k1];
            float cm0 = 3.4e38f, cm1 = 3.4e38f;
#pragma unroll
            for (int j = 0; j < 8; ++j) {
                float f0 = fmaf(psx[j], qx0, fmaf(psy[j], qy0, psz[j] * qz0));
                float f1 = fmaf(psx[j], qx1, fmaf(psy[j], qy1, psz[j] * qz1));
                rowacc[j] = fminf(fminf(rowacc[j], hg0 + f0), hg1 + f1);
                cm0 = fminf(cm0, s2[j] + f0);
                cm1 = fminf(cm1, s2[j] + f1);
            }
            cm0 = fminf(cm0, __shfl_xor(cm0, 1));
            cm0 = fminf(cm0, __shfl_xor(cm0, 2));
            cm0 = fminf(cm0, __shfl_xor(cm0, 4));
            cm0 = fminf(cm0, __shfl_xor(cm0, 8));
            cm1 = fminf(cm1, __shfl_xor(cm1, 1));
            cm1 = fminf(cm1, __shfl_xor(cm1, 2));
            cm1 = fminf(cm1, __shfl_xor(cm1, 4));
            cm1 = fminf(cm1, __shfl_xor(cm1, 8));
            if (ts == 0)
                d2acc += sqrtf(fmaxf(hg0 + cm0, FEPS)) + sqrtf(fmaxf(hg1 + cm1, FEPS));
        }
        if (tk < 8) {
            int k = 192 + tk;
            float qx0 = gx[k], qy0 = gy[k], qz0 = gz[k], hg0 = g2s[k];
            float cm0 = 3.4e38f;
#pragma unroll
            for (int j = 0; j < 8; ++j) {
                float f0 = fmaf(psx[j], qx0, fmaf(psy[j], qy0, psz[j] * qz0));
                rowacc[j] = fminf(rowacc[j], hg0 + f0);
                cm0 = fminf(cm0, s2[j] + f0);
            }
            cm0 = fminf(cm0, __shfl_xor(cm0, 1));
            cm0 = fminf(cm0, __shfl_xor(cm0, 2));
            cm0 = fminf(cm0, __shfl_xor(cm0, 4));
            cm0 = fminf(cm0, __shfl_xor(cm0, 8));
            if (ts == 0) d2acc += sqrtf(fmaxf(hg0 + cm0, FEPS));
        }
#pragma unroll
        for (int j = 0; j < 8; ++j) {
            rowacc[j] = fminf(rowacc[j], __shfl_xor(rowacc[j], 16));
            rowacc[j] = fminf(rowacc[j], __shfl_xor(rowacc[j], 32));
            rowacc[j] += s2[j];
        }
        float* rowred = (float*)hist;   // reuse hist LDS: [4][128] floats
        if (l < 16) {
#pragma unroll
            for (int j = 0; j < 8; ++j) rowred[w * NS + l * 8 + j] = rowacc[j];
        }
        __syncthreads();
        float d1v = 0.0f;
        if (tid < NS) {
            float m = fminf(fminf(rowred[tid], rowred[NS + tid]),
                            fminf(rowred[2 * NS + tid], rowred[3 * NS + tid]));
            d1v = sqrtf(fmaxf(m, FEPS));
        }
        float t1 = block_sum_f(d1v, redf);
        float t2 = block_sum_f(d2acc, redf);
        if (tid == 0) {
            atomicExch(&ws[2 * bn], t1);
            atomicExch(&ws[2 * bn + 1], t2);
        }
    }

    // ---- epilogue: last finishing block reduces all partials ----
    __threadfence();
    if (tid == 0) {
        unsigned old = atomicAdd((unsigned*)(ws + CNT_OFF), 1u);
        lastFlag = (old == GRID_TOTAL - 1);
    }
    __syncthreads();
    if (lastFlag) {
        float s1 = 0.0f, s2v = 0.0f, s3 = 0.0f, s4 = 0.0f;
#pragma unroll
        for (int j = 0; j < GROUP_BLOCKS / 256; ++j) {
            int idx = tid + j * 256;
            s1 += atomicAdd(&ws[2 * idx], 0.0f);          // coherent read
            s2v += atomicAdd(&ws[2 * idx + 1], 0.0f);
            s3 += atomicAdd(&ws[CD1A_OFF + idx], 0.0f);
        }
        s4 = atomicAdd(&ws[T4_OFF + tid], 0.0f);
        for (int o = 32; o; o >>= 1) {
            s1 += __shfl_xor(s1, o);
            s2v += __shfl_xor(s2v, o);
            s3 += __shfl_xor(s3, o);
            s4 += __shfl_xor(s4, o);
        }
        float* fred = (float*)hist;     // reuse LDS: [4][4]
        if (l == 0) {
            fred[w * 4 + 0] = s1; fred[w * 4 + 1] = s2v;
            fred[w * 4 + 2] = s3; fred[w * 4 + 3] = s4;
        }
        __syncthreads();
        if (tid == 0) {
            float t1 = 0.0f, t2 = 0.0f, t3 = 0.0f, t4 = 0.0f;
#pragma unroll
            for (int j = 0; j < 4; ++j) {
                t1 += fred[j * 4 + 0]; t2 += fred[j * 4 + 1];
                t3 += fred[j * 4 + 2]; t4 += fred[j * 4 + 3];
            }
            float cd2 = 0.5f * (t1 / ((float)NB * NS) + t2 / ((float)NB * NK));
            float cd1 = 0.5f * (t3 / ((float)NB * NN) + t4 / ((float)NB * NM));
            out[0] = cd2 * 1000.0f;
            out[1] = cd1 * 1000.0f;
            out[2] = cd2 * 1000.0f;
        }
    }
}

extern "C" void kernel_launch(void* const* d_in, const int* in_sizes, int n_in,
                              void* d_out, int out_size, void* d_ws, size_t ws_size,
                              hipStream_t stream) {
    const float* means = (const float*)d_in[0];
    const float* sp    = (const float*)d_in[1];
    const float* gt    = (const float*)d_in[2];
    float* out = (float*)d_out;
    float* ws  = (float*)d_ws;

    hipMemsetAsync(ws + CNT_OFF, 0, sizeof(unsigned), stream);
    k_main<<<GRID_TOTAL, 256, 0, stream>>>(means, sp, gt, ws, out);
}

// Round 17
// 133.949 us; speedup vs baseline: 1.9086x; 1.9086x over previous
//
#include <hip/hip_runtime.h>

#define NB 8
#define NN 256
#define NS 128
#define NM 8192
#define NK 200
#define KP1 201
#define FEPS 1e-9f
#define GROUP_BLOCKS (NB * NN)   // 2048 group units
#define CD1B_BLOCKS 128          // 512-thread blocks; 8 batches x 16 chunks
#define NT 512                   // threads per block (8 waves)
#define HBINS 2048

// ws layout (floats):
//  [0    .. 4096)  float2 per group unit {t1, t2}    (cd2 partials)
//  [4096 .. 6144)  float per group unit  cd1a        (cd1 term 1)
//  [6144 .. 6272)  float per cd1b block  t4          (cd1 term 2, 128 slots)

// ---------- reduction helpers (512 threads = 8 waves) ----------
__device__ __forceinline__ float block_sum_f(float v, float* redf) {
    const int tid = threadIdx.x, w = tid >> 6, l = tid & 63;
    for (int o = 32; o; o >>= 1) v += __shfl_xor(v, o);
    if (l == 0) redf[w] = v;
    __syncthreads();
    float t = 0.0f;
#pragma unroll
    for (int j = 0; j < 8; ++j) t += redf[j];
    __syncthreads();
    return t;
}

__device__ __forceinline__ int block_excl_scan_i(int v, int* redi, int tid, int& total) {
    const int l = tid & 63, w = tid >> 6;
    int x = v;
    for (int o = 1; o < 64; o <<= 1) { int y = __shfl_up(x, o); if (l >= o) x += y; }
    if (l == 63) redi[w] = x;
    __syncthreads();
    int woff = 0, tot = 0;
#pragma unroll
    for (int j = 0; j < 8; ++j) { if (j < w) woff += redi[j]; tot += redi[j]; }
    total = tot;
    int ex = woff + x - v;
    __syncthreads();
    return ex;
}

__device__ __forceinline__ int find_bin(int* hist, int nbins, int& rem,
                                        int* redi, int* ibc, int tid) {
    const int C = nbins >> 9;            // bins per thread
    const int CC = C ? C : 1;
    const int base = tid * CC;
    int local = 0;
    for (int j = 0; j < CC; ++j) local += hist[base + j];
    int total;
    int ex = block_excl_scan_i(local, redi, tid, total);
    if (ex < rem && rem <= ex + local) {
        int run = ex;
        for (int j = 0; j < CC; ++j) {
            int h = hist[base + j];
            if (run + h >= rem) { ibc[0] = base + j; ibc[1] = rem - run; break; }
            run += h;
        }
    }
    __syncthreads();
    int bin = ibc[0]; rem = ibc[1];
    __syncthreads();
    return bin;
}

// ---------- fused kernel: 2048 group blocks + 128 cd1b blocks, 512 threads ----------
__global__ __launch_bounds__(NT)        // NATURAL allocation (R15's (NT,8) clamp spilled)
void k_main(const float* __restrict__ means, const float* __restrict__ sp,
            const float* __restrict__ gt, float* __restrict__ ws) {
    __shared__ int   hist[HBINS];                 // 8KB; reused: rowred, cd1b mpool
    __shared__ float gx[NK], gy[NK], gz[NK], g2s[NK];
    __shared__ float sx[NS], sy[NS], sz[NS];
    __shared__ float redf[8];
    __shared__ int   redi[8];
    __shared__ int   ibc[2];

    const int tid = threadIdx.x;
    const int w = tid >> 6, l = tid & 63;

    if (blockIdx.x >= GROUP_BLOCKS) {
        // ---- cd1 term 2: per (b,m) min over the 256 means; 512 m's per block ----
        const int blk = blockIdx.x - GROUP_BLOCKS;   // 0..127
        const int b = blk >> 4;
        const int m = ((blk & 15) << 9) + tid;
        float* mxs = (float*)hist;                   // 768 floats in 8KB pool
        float* mys = mxs + NN;
        float* mzs = mys + NN;
        const float* mb = means + (size_t)b * NN * 3;
        if (tid < NN) {
            mxs[tid] = mb[tid * 3 + 0];
            mys[tid] = mb[tid * 3 + 1];
            mzs[tid] = mb[tid * 3 + 2];
        }
        __syncthreads();
        const float* gp = gt + ((size_t)b * NM + m) * 3;
        const float px = gp[0], py = gp[1], pz = gp[2];
        float mn = 3.4e38f;
#pragma unroll 8
        for (int n = 0; n < NN; ++n) {
            float dx = px - mxs[n], dy = py - mys[n], dz = pz - mzs[n];
            mn = fminf(mn, fmaf(dx, dx, fmaf(dy, dy, dz * dz)));
        }
        float d2 = sqrtf(fmaxf(mn, FEPS));
        float t4 = block_sum_f(d2, redf);
        if (tid == 0) ws[3 * GROUP_BLOCKS + blk] = t4;
        return;
    }

    // ---- group path: one block per (b,n) ----
    const int bn = blockIdx.x;
    const int b  = bn >> 8;

    const float* spb = sp + (size_t)bn * NS * 3;
    if (tid < NS) {
        sx[tid] = spb[tid * 3 + 0];
        sy[tid] = spb[tid * 3 + 1];
        sz[tid] = spb[tid * 3 + 2];
    }
    const float mx = means[bn * 3 + 0];
    const float my = means[bn * 3 + 1];
    const float mz = means[bn * 3 + 2];
    const float* g = gt + (size_t)b * NM * 3;

    // ---- distances: contiguous float4 loads; thread owns m in [tid*16, tid*16+16) ----
    const float* gtb = g + tid * 48;              // 48 floats = 16 points, 16B-aligned
    float vd[16];
    float vmin = 3.4e38f; int varg = -1;
#pragma unroll 2                                  // cap in-flight dwordx4 (register pressure)
    for (int c = 0; c < 4; ++c) {
        float4 f0 = *(const float4*)(gtb + c * 12);
        float4 f1 = *(const float4*)(gtb + c * 12 + 4);
        float4 f2 = *(const float4*)(gtb + c * 12 + 8);
        float px[4] = {f0.x, f0.w, f1.z, f2.y};
        float py[4] = {f0.y, f1.x, f1.w, f2.z};
        float pz[4] = {f0.z, f1.y, f2.x, f2.w};
#pragma unroll
        for (int j = 0; j < 4; ++j) {
            int i = c * 4 + j;
            float dx = mx - px[j], dy = my - py[j], dz = mz - pz[j];
            float d = fmaf(dx, dx, fmaf(dy, dy, dz * dz));
            vd[i] = d;
            if (d < vmin) { vmin = d; varg = tid * 16 + i; }  // lowest m kept on ties
        }
    }

    // block argmin (value,index), lowest index on ties
    for (int o = 32; o; o >>= 1) {
        float ov = __shfl_xor(vmin, o);
        int   oi = __shfl_xor(varg, o);
        if (ov < vmin || (ov == vmin && oi < varg)) { vmin = ov; varg = oi; }
    }
    if (l == 0) { redf[w] = vmin; redi[w] = varg; }
    __syncthreads();
    float dmin = redf[0]; int m0 = redi[0];
#pragma unroll
    for (int i = 1; i < 8; ++i) {
        if (redf[i] < dmin || (redf[i] == dmin && redi[i] < m0)) { dmin = redf[i]; m0 = redi[i]; }
    }
    if (tid == 0) ws[2 * GROUP_BLOCKS + bn] = sqrtf(fmaxf(dmin, FEPS));
    __syncthreads();

    // ---- exact 201st-smallest via 3-level histogram radix ----
    int rem = KP1;
    unsigned prefix;
    for (int j = tid; j < HBINS; j += NT) hist[j] = 0;
    __syncthreads();
#pragma unroll
    for (int i = 0; i < 16; ++i) atomicAdd(&hist[__float_as_uint(vd[i]) >> 20], 1);
    __syncthreads();
    prefix = (unsigned)find_bin(hist, 2048, rem, redi, ibc, tid);
    for (int j = tid; j < HBINS; j += NT) hist[j] = 0;
    __syncthreads();
#pragma unroll
    for (int i = 0; i < 16; ++i) {
        unsigned u = __float_as_uint(vd[i]);
        if ((u >> 20) == prefix) atomicAdd(&hist[(u >> 9) & 2047], 1);
    }
    __syncthreads();
    prefix = (prefix << 11) | (unsigned)find_bin(hist, 2048, rem, redi, ibc, tid);
    for (int j = tid; j < 512; j += NT) hist[j] = 0;
    __syncthreads();
#pragma unroll
    for (int i = 0; i < 16; ++i) {
        unsigned u = __float_as_uint(vd[i]);
        if ((u >> 9) == prefix) atomicAdd(&hist[u & 511], 1);
    }
    __syncthreads();
    const unsigned X = (prefix << 9) | (unsigned)find_bin(hist, 512, rem, redi, ibc, tid);

    // ---- gather: strict-less via scan, ties fill; |g|^2 into LDS ----
    int c = 0;
#pragma unroll
    for (int i = 0; i < 16; ++i) {
        int m = tid * 16 + i;
        c += (m != m0 && __float_as_uint(vd[i]) < X);
    }
    int total;
    int p = block_excl_scan_i(c, redi, tid, total);
#pragma unroll
    for (int i = 0; i < 16; ++i) {
        int m = tid * 16 + i;
        if (m != m0 && __float_as_uint(vd[i]) < X) {
            float x = g[m * 3 + 0], y = g[m * 3 + 1], z = g[m * 3 + 2];
            gx[p] = x; gy[p] = y; gz[p] = z;
            g2s[p] = fmaf(x, x, fmaf(y, y, z * z));
            ++p;
        }
    }
    if (tid == 0) ibc[0] = total;
    __syncthreads();
#pragma unroll
    for (int i = 0; i < 16; ++i) {
        int m = tid * 16 + i;
        if (m != m0 && __float_as_uint(vd[i]) == X) {
            int q = atomicAdd(&ibc[0], 1);
            if (q < NK) {
                float x = g[m * 3 + 0], y = g[m * 3 + 1], z = g[m * 3 + 2];
                gx[q] = x; gy[q] = y; gz[q] = z;
                g2s[q] = fmaf(x, x, fmaf(y, y, z * z));
            }
        }
    }
    __syncthreads();

    // ---- fused chamfer via d = |s|^2 + |g|^2 - 2 s.g ----
    // thread (ts, tk) = (tid&31, tid>>5): 4 s-rows in regs x 16 k-col slots.
    const int ts = tid & 31, tk = tid >> 5;
    float psx[4], psy[4], psz[4], s2[4];
#pragma unroll
    for (int j = 0; j < 4; ++j) {
        int s = ts * 4 + j;
        float x = sx[s], y = sy[s], z = sz[s];
        s2[j] = fmaf(x, x, fmaf(y, y, z * z));
        psx[j] = -2.0f * x; psy[j] = -2.0f * y; psz[j] = -2.0f * z;
    }
    float rowacc[4];
#pragma unroll
    for (int j = 0; j < 4; ++j) rowacc[j] = 3.4e38f;
    float d2acc = 0.0f;
    // 12 uniform k-columns per thread (covers k in [0,192))
#pragma unroll 4
    for (int ip = 0; ip < 12; ++ip) {
        int k = tk + 16 * ip;
        float qx = gx[k], qy = gy[k], qz = gz[k], hg = g2s[k];
        float cm = 3.4e38f;
#pragma unroll
        for (int j = 0; j < 4; ++j) {
            float f = fmaf(psx[j], qx, fmaf(psy[j], qy, psz[j] * qz));  // -2 s.g
            rowacc[j] = fminf(rowacc[j], hg + f);
            cm = fminf(cm, s2[j] + f);
        }
        cm = fminf(cm, __shfl_xor(cm, 1));
        cm = fminf(cm, __shfl_xor(cm, 2));
        cm = fminf(cm, __shfl_xor(cm, 4));
        cm = fminf(cm, __shfl_xor(cm, 8));
        cm = fminf(cm, __shfl_xor(cm, 16));
        if (ts == 0) d2acc += sqrtf(fmaxf(hg + cm, FEPS));
    }
    // leftover column k = 192 + tk (tk < 8; uniform per 32-lane half-wave)
    if (tk < 8) {
        int k = 192 + tk;
        float qx = gx[k], qy = gy[k], qz = gz[k], hg = g2s[k];
        float cm = 3.4e38f;
#pragma unroll
        for (int j = 0; j < 4; ++j) {
            float f = fmaf(psx[j], qx, fmaf(psy[j], qy, psz[j] * qz));
            rowacc[j] = fminf(rowacc[j], hg + f);
            cm = fminf(cm, s2[j] + f);
        }
        cm = fminf(cm, __shfl_xor(cm, 1));
        cm = fminf(cm, __shfl_xor(cm, 2));
        cm = fminf(cm, __shfl_xor(cm, 4));
        cm = fminf(cm, __shfl_xor(cm, 8));
        cm = fminf(cm, __shfl_xor(cm, 16));
        if (ts == 0) d2acc += sqrtf(fmaxf(hg + cm, FEPS));
    }
    // row-min: combine the wave's two tk halves (lane l <-> l^32 share ts); add |s|^2
#pragma unroll
    for (int j = 0; j < 4; ++j) {
        rowacc[j] = fminf(rowacc[j], __shfl_xor(rowacc[j], 32));
        rowacc[j] += s2[j];
    }
    float* rowred = (float*)hist;   // reuse hist LDS: [8][128] floats
    if (l < 32) {                   // lane l<32 has ts == l
#pragma unroll
        for (int j = 0; j < 4; ++j) rowred[w * NS + l * 4 + j] = rowacc[j];
    }
    __syncthreads();
    float d1v = 0.0f;
    if (tid < NS) {
        float m = rowred[tid];
#pragma unroll
        for (int j = 1; j < 8; ++j) m = fminf(m, rowred[j * NS + tid]);
        d1v = sqrtf(fmaxf(m, FEPS));
    }
    float t1 = block_sum_f(d1v, redf);
    float t2 = block_sum_f(d2acc, redf);
    if (tid == 0) {
        float2* wsA = (float2*)ws;
        wsA[bn] = make_float2(t1, t2);
    }
}

// ---------- featherweight finalize ----------
__global__ __launch_bounds__(256)
void k_fin(const float* __restrict__ ws, float* __restrict__ out) {
    __shared__ float red[4][4];
    const int tid = threadIdx.x, w = tid >> 6, l = tid & 63;
    float s1 = 0.0f, s2 = 0.0f, s3 = 0.0f, s4 = 0.0f;
    const float2* wsA = (const float2*)ws;
#pragma unroll
    for (int j = 0; j < GROUP_BLOCKS / 256; ++j) {
        float2 v = wsA[tid + j * 256];
        s1 += v.x; s2 += v.y;
        s3 += ws[2 * GROUP_BLOCKS + tid + j * 256];
    }
    s4 = (tid < CD1B_BLOCKS) ? ws[3 * GROUP_BLOCKS + tid] : 0.0f;
    for (int o = 32; o; o >>= 1) {
        s1 += __shfl_xor(s1, o);
        s2 += __shfl_xor(s2, o);
        s3 += __shfl_xor(s3, o);
        s4 += __shfl_xor(s4, o);
    }
    if (l == 0) { red[w][0] = s1; red[w][1] = s2; red[w][2] = s3; red[w][3] = s4; }
    __syncthreads();
    if (tid == 0) {
        float t1 = 0.0f, t2 = 0.0f, t3 = 0.0f, t4 = 0.0f;
#pragma unroll
        for (int j = 0; j < 4; ++j) {
            t1 += red[j][0]; t2 += red[j][1]; t3 += red[j][2]; t4 += red[j][3];
        }
        float cd2 = 0.5f * (t1 / ((float)NB * NS) + t2 / ((float)NB * NK));
        float cd1 = 0.5f * (t3 / ((float)NB * NN) + t4 / ((float)NB * NM));
        out[0] = cd2 * 1000.0f;
        out[1] = cd1 * 1000.0f;
        out[2] = cd2 * 1000.0f;
    }
}

extern "C" void kernel_launch(void* const* d_in, const int* in_sizes, int n_in,
                              void* d_out, int out_size, void* d_ws, size_t ws_size,
                              hipStream_t stream) {
    const float* means = (const float*)d_in[0];
    const float* sp    = (const float*)d_in[1];
    const float* gt    = (const float*)d_in[2];
    float* out = (float*)d_out;
    float* ws  = (float*)d_ws;

    k_main<<<GROUP_BLOCKS + CD1B_BLOCKS, NT, 0, stream>>>(means, sp, gt, ws);
    k_fin<<<1, 256, 0, stream>>>(ws, out);
}